// Round 1
// baseline (245.664 us; speedup 1.0000x reference)
//
#include <hip/hip_runtime.h>
#include <math.h>

namespace {

constexpr int BSZ = 2, LEN = 2048, DIM = 2048, NST = 16, RNK = 128;
constexpr int NC = 32, CHUNK = LEN / NC;          // 32 chunks of 64
constexpr float LOG2E = 1.4426950408889634f;

__device__ __forceinline__ float fast_exp2(float x) {
#if __has_builtin(__builtin_amdgcn_exp2f)
  return __builtin_amdgcn_exp2f(x);
#else
  return exp2f(x);
#endif
}

// ---------- Kernel 1: dt = softplus(delta @ W^T + b_dt), (B*L, D) ----------
constexpr int BM = 64, BN = 64, LDT = RNK + 4;    // 132 floats/row keeps 16B align, breaks pow2 stride

__global__ __launch_bounds__(256)
void dt_gemm_softplus(const float* __restrict__ delta, const float* __restrict__ W,
                      const float* __restrict__ bias, float* __restrict__ dtout) {
  __shared__ float dl[BM * LDT];
  __shared__ float wl[BN * LDT];
  const int tid = threadIdx.x;
  const int bm = blockIdx.x & 63;                 // (B*L)/BM = 64
  const int bn = blockIdx.x >> 6;                 // D/BN = 32
  const float4* dsrc = (const float4*)(delta + (size_t)bm * BM * RNK);
  const float4* wsrc = (const float4*)(W + (size_t)bn * BN * RNK);
#pragma unroll
  for (int i = 0; i < 8; ++i) {                   // 64 rows x 128 cols = 2048 float4 per operand
    int idx4 = tid + i * 256;
    int row = idx4 >> 5;
    int col = (idx4 & 31) << 2;
    *(float4*)&dl[row * LDT + col] = dsrc[idx4];
    *(float4*)&wl[row * LDT + col] = wsrc[idx4];
  }
  __syncthreads();
  const int tm = tid >> 4, tn = tid & 15;
  float acc[4][4] = {};
#pragma unroll 4
  for (int k = 0; k < RNK; k += 4) {
    float4 a[4], b[4];
#pragma unroll
    for (int i = 0; i < 4; ++i) a[i] = *(const float4*)&dl[(tm * 4 + i) * LDT + k];
#pragma unroll
    for (int j = 0; j < 4; ++j) b[j] = *(const float4*)&wl[(tn * 4 + j) * LDT + k];
#pragma unroll
    for (int i = 0; i < 4; ++i)
#pragma unroll
      for (int j = 0; j < 4; ++j) {
        acc[i][j] = fmaf(a[i].x, b[j].x, acc[i][j]);
        acc[i][j] = fmaf(a[i].y, b[j].y, acc[i][j]);
        acc[i][j] = fmaf(a[i].z, b[j].z, acc[i][j]);
        acc[i][j] = fmaf(a[i].w, b[j].w, acc[i][j]);
      }
  }
#pragma unroll
  for (int i = 0; i < 4; ++i) {
    const int m = bm * BM + tm * 4 + i;
#pragma unroll
    for (int j = 0; j < 4; ++j) {
      const int d = bn * BN + tn * 4 + j;
      float z = acc[i][j] + bias[d];
      // stable softplus: max(z,0) + log1p(exp(-|z|))
      float sp = fmaxf(z, 0.f) + log1pf(__expf(-fabsf(z)));
      dtout[(size_t)m * DIM + d] = sp;
    }
  }
}

// ---------- Kernel 2: per-chunk local scan -> P (decay product), S (local state) ----------
// thread = one d; block = 256 d's for one (b, chunk)
__global__ __launch_bounds__(256)
void scan_pass1(const float* __restrict__ dtw, const float* __restrict__ x,
                const float* __restrict__ Bin, const float* __restrict__ Alog,
                float* __restrict__ Pout, float* __restrict__ Sout) {
  __shared__ float4 Bl[CHUNK * NST / 4];          // 256 float4 = 64 steps x 16 n
  const int tid = threadIdx.x;
  const int bz = blockIdx.x;
  const int dt8 = bz & 7;                         // D/256 = 8
  const int c = (bz >> 3) & (NC - 1);
  const int b = bz >> 8;
  const int d = dt8 * 256 + tid;
  const int l0 = c * CHUNK;

  Bl[tid] = ((const float4*)(Bin + ((size_t)b * LEN + l0) * NST))[tid];

  float A2[NST];
  {
    const float4* ap = (const float4*)(Alog + (size_t)d * NST);
#pragma unroll
    for (int q = 0; q < 4; ++q) {
      float4 v = ap[q];
      A2[q * 4 + 0] = -expf(v.x) * LOG2E;
      A2[q * 4 + 1] = -expf(v.y) * LOG2E;
      A2[q * 4 + 2] = -expf(v.z) * LOG2E;
      A2[q * 4 + 3] = -expf(v.w) * LOG2E;
    }
  }
  __syncthreads();

  float h[NST];
#pragma unroll
  for (int n = 0; n < NST; ++n) h[n] = 0.f;
  float sdt = 0.f;
  const float* dtp = dtw + ((size_t)b * LEN + l0) * DIM + d;
  const float* xp  = x   + ((size_t)b * LEN + l0) * DIM + d;

#pragma unroll 4
  for (int i = 0; i < CHUNK; ++i) {
    float dt = dtp[(size_t)i * DIM];
    float xv = xp[(size_t)i * DIM];
    float dtx = dt * xv;
    sdt += dt;
#pragma unroll
    for (int q = 0; q < 4; ++q) {
      float4 Bv = Bl[i * 4 + q];
      float e0 = fast_exp2(dt * A2[q * 4 + 0]);
      float e1 = fast_exp2(dt * A2[q * 4 + 1]);
      float e2 = fast_exp2(dt * A2[q * 4 + 2]);
      float e3 = fast_exp2(dt * A2[q * 4 + 3]);
      h[q * 4 + 0] = fmaf(e0, h[q * 4 + 0], dtx * Bv.x);
      h[q * 4 + 1] = fmaf(e1, h[q * 4 + 1], dtx * Bv.y);
      h[q * 4 + 2] = fmaf(e2, h[q * 4 + 2], dtx * Bv.z);
      h[q * 4 + 3] = fmaf(e3, h[q * 4 + 3], dtx * Bv.w);
    }
  }

  const size_t obase = ((size_t)(b * NC + c) * DIM + d) * NST;
#pragma unroll
  for (int q = 0; q < 4; ++q) {
    // chunk decay product: exp2(A2 * sum(dt)) -- exact same product as per-step factors
    float4 pv;
    pv.x = fast_exp2(sdt * A2[q * 4 + 0]);
    pv.y = fast_exp2(sdt * A2[q * 4 + 1]);
    pv.z = fast_exp2(sdt * A2[q * 4 + 2]);
    pv.w = fast_exp2(sdt * A2[q * 4 + 3]);
    *(float4*)&Pout[obase + q * 4] = pv;
    float4 sv = {h[q * 4 + 0], h[q * 4 + 1], h[q * 4 + 2], h[q * 4 + 3]};
    *(float4*)&Sout[obase + q * 4] = sv;
  }
}

// ---------- Kernel 3: sequential combine over chunks; h_init written over P ----------
__global__ __launch_bounds__(256)
void chunk_combine(float* __restrict__ P, const float* __restrict__ S) {
  const int t = blockIdx.x * 256 + threadIdx.x;   // B*D*N = 65536 threads
  const int n = t & (NST - 1);
  const int d = (t >> 4) & (DIM - 1);
  const int b = t >> 15;
  float cur = 0.f;
#pragma unroll
  for (int c = 0; c < NC; ++c) {
    const size_t idx = ((size_t)(b * NC + c) * DIM + d) * NST + n;
    float p = P[idx];
    float s = S[idx];
    P[idx] = cur;                                  // h_init for chunk c
    cur = fmaf(p, cur, s);
  }
}

// ---------- Kernel 4: re-scan each chunk from h_init, emit y + x*D ----------
__global__ __launch_bounds__(256)
void scan_pass2(const float* __restrict__ dtw, const float* __restrict__ x,
                const float* __restrict__ Bin, const float* __restrict__ Cin,
                const float* __restrict__ Alog, const float* __restrict__ Dpar,
                const float* __restrict__ Hin, float* __restrict__ out) {
  __shared__ float4 Bl[CHUNK * NST / 4];
  __shared__ float4 Cl[CHUNK * NST / 4];
  const int tid = threadIdx.x;
  const int bz = blockIdx.x;
  const int dt8 = bz & 7;
  const int c = (bz >> 3) & (NC - 1);
  const int b = bz >> 8;
  const int d = dt8 * 256 + tid;
  const int l0 = c * CHUNK;

  Bl[tid] = ((const float4*)(Bin + ((size_t)b * LEN + l0) * NST))[tid];
  Cl[tid] = ((const float4*)(Cin + ((size_t)b * LEN + l0) * NST))[tid];

  float A2[NST];
  {
    const float4* ap = (const float4*)(Alog + (size_t)d * NST);
#pragma unroll
    for (int q = 0; q < 4; ++q) {
      float4 v = ap[q];
      A2[q * 4 + 0] = -expf(v.x) * LOG2E;
      A2[q * 4 + 1] = -expf(v.y) * LOG2E;
      A2[q * 4 + 2] = -expf(v.z) * LOG2E;
      A2[q * 4 + 3] = -expf(v.w) * LOG2E;
    }
  }

  const size_t obase = ((size_t)(b * NC + c) * DIM + d) * NST;
  float h[NST];
#pragma unroll
  for (int q = 0; q < 4; ++q) {
    float4 hv = *(const float4*)&Hin[obase + q * 4];
    h[q * 4 + 0] = hv.x; h[q * 4 + 1] = hv.y; h[q * 4 + 2] = hv.z; h[q * 4 + 3] = hv.w;
  }
  const float dpar = Dpar[d];
  __syncthreads();

  const float* dtp = dtw + ((size_t)b * LEN + l0) * DIM + d;
  const float* xp  = x   + ((size_t)b * LEN + l0) * DIM + d;
  float* op        = out + ((size_t)b * LEN + l0) * DIM + d;

#pragma unroll 4
  for (int i = 0; i < CHUNK; ++i) {
    float dt = dtp[(size_t)i * DIM];
    float xv = xp[(size_t)i * DIM];
    float dtx = dt * xv;
    float y0 = 0.f, y1 = 0.f, y2 = 0.f, y3 = 0.f;
#pragma unroll
    for (int q = 0; q < 4; ++q) {
      float4 Bv = Bl[i * 4 + q];
      float4 Cv = Cl[i * 4 + q];
      float e0 = fast_exp2(dt * A2[q * 4 + 0]);
      float e1 = fast_exp2(dt * A2[q * 4 + 1]);
      float e2 = fast_exp2(dt * A2[q * 4 + 2]);
      float e3 = fast_exp2(dt * A2[q * 4 + 3]);
      float hh0 = fmaf(e0, h[q * 4 + 0], dtx * Bv.x);
      float hh1 = fmaf(e1, h[q * 4 + 1], dtx * Bv.y);
      float hh2 = fmaf(e2, h[q * 4 + 2], dtx * Bv.z);
      float hh3 = fmaf(e3, h[q * 4 + 3], dtx * Bv.w);
      h[q * 4 + 0] = hh0; h[q * 4 + 1] = hh1; h[q * 4 + 2] = hh2; h[q * 4 + 3] = hh3;
      float yq = hh0 * Cv.x;
      yq = fmaf(hh1, Cv.y, yq);
      yq = fmaf(hh2, Cv.z, yq);
      yq = fmaf(hh3, Cv.w, yq);
      if (q == 0) y0 = yq; else if (q == 1) y1 = yq; else if (q == 2) y2 = yq; else y3 = yq;
    }
    op[(size_t)i * DIM] = fmaf(xv, dpar, (y0 + y1) + (y2 + y3));
  }
}

}  // namespace

extern "C" void kernel_launch(void* const* d_in, const int* in_sizes, int n_in,
                              void* d_out, int out_size, void* d_ws, size_t ws_size,
                              hipStream_t stream) {
  const float* x     = (const float*)d_in[0];
  const float* delta = (const float*)d_in[1];
  const float* Bin   = (const float*)d_in[2];
  const float* Cin   = (const float*)d_in[3];
  const float* Wdt   = (const float*)d_in[4];
  const float* bdt   = (const float*)d_in[5];
  const float* Alog  = (const float*)d_in[6];
  const float* Dpar  = (const float*)d_in[7];
  float* out = (float*)d_out;

  char* ws = (char*)d_ws;
  float* dtw = (float*)ws;                                        // B*L*D f32 = 32 MiB
  float* P   = (float*)(ws + (size_t)BSZ * LEN * DIM * 4);        // B*NC*D*N = 8 MiB
  float* S   = P + (size_t)BSZ * NC * DIM * NST;                  // 8 MiB

  dt_gemm_softplus<<<(BSZ * LEN / BM) * (DIM / BN), 256, 0, stream>>>(delta, Wdt, bdt, dtw);
  scan_pass1<<<BSZ * NC * (DIM / 256), 256, 0, stream>>>(dtw, x, Bin, Alog, P, S);
  chunk_combine<<<BSZ * DIM * NST / 256, 256, 0, stream>>>(P, S);
  scan_pass2<<<BSZ * NC * (DIM / 256), 256, 0, stream>>>(dtw, x, Bin, Cin, Alog, Dpar, P, out);
}

// Round 3
// 185.030 us; speedup vs baseline: 1.3277x; 1.3277x over previous
//
#include <hip/hip_runtime.h>
#include <hip/hip_bf16.h>
#include <math.h>

namespace {

constexpr int BSZ = 2, LEN = 2048, DIM = 2048, NST = 16, RNK = 128;
constexpr int NC = 64, CHUNK = LEN / NC;          // 64 chunks of 32
constexpr int KS = 3 * RNK;                       // split-K = 384
constexpr float LOG2E = 1.4426950408889634f;
constexpr float LN2 = 0.6931471805599453f;

using bf16x8 = __attribute__((ext_vector_type(8))) short;
using f32x4  = __attribute__((ext_vector_type(4))) float;

__device__ __forceinline__ float fast_exp2(float x) {
#if __has_builtin(__builtin_amdgcn_exp2f)
  return __builtin_amdgcn_exp2f(x);
#else
  return exp2f(x);
#endif
}

__device__ __forceinline__ unsigned short bf16_rne(float x) {
  __hip_bfloat16 h = __float2bfloat16(x);
  return *(unsigned short*)&h;
}
__device__ __forceinline__ float bf16_tof(unsigned short u) {
  __hip_bfloat16 h = *(__hip_bfloat16*)&u;
  return __bfloat162float(h);
}

// ---------- Kernel 0: split f32 -> bf16 hi/lo, padded K=384 layouts ----------
// Ad: [B*L=4096][384] = [hi | lo | hi];  Bd: [D=2048][384] = [hi | hi | lo]
__global__ __launch_bounds__(256)
void split_bf16(const float* __restrict__ delta, const float* __restrict__ W,
                unsigned short* __restrict__ Ad, unsigned short* __restrict__ Bd) {
  int t = blockIdx.x * 256 + threadIdx.x;
  const int NA = BSZ * LEN * RNK;                 // 524288
  if (t < NA) {
    int row = t >> 7, k = t & (RNK - 1);
    float x = delta[t];
    unsigned short hi = bf16_rne(x);
    unsigned short lo = bf16_rne(x - bf16_tof(hi));
    unsigned short* p = Ad + (size_t)row * KS;
    p[k] = hi; p[RNK + k] = lo; p[2 * RNK + k] = hi;
  } else {
    t -= NA;                                      // 262144 W elements
    int row = t >> 7, k = t & (RNK - 1);
    float x = W[t];
    unsigned short hi = bf16_rne(x);
    unsigned short lo = bf16_rne(x - bf16_tof(hi));
    unsigned short* p = Bd + (size_t)row * KS;
    p[k] = hi; p[RNK + k] = hi; p[2 * RNK + k] = lo;
  }
}

// ---------- Kernel 1: dt = softplus(A' @ B'^T + bias) via bf16 MFMA ----------
// block = 256 thr (4 waves, 2x2), tile 128x128; wave tile 64x64 (4x4 frags of 16x16)
// No LDS: A'/B' total 4.5MB -> L2/L3 resident; lanes load 16B fragments directly.
__global__ __launch_bounds__(256)
void dt_mfma(const unsigned short* __restrict__ Ad, const unsigned short* __restrict__ Bd,
             const float* __restrict__ bias, float* __restrict__ dtout) {
  const int lane = threadIdx.x & 63, wid = threadIdx.x >> 6;
  const int wm = wid >> 1, wn = wid & 1;
  const int bm = blockIdx.x & 31, bn = blockIdx.x >> 5;   // M/128=32, N/128=16
  const int r = lane & 15, kg = lane >> 4;

  const unsigned short* arow = Ad + (size_t)(bm * 128 + wm * 64 + r) * KS + kg * 8;
  const unsigned short* brow = Bd + (size_t)(bn * 128 + wn * 64 + r) * KS + kg * 8;

  f32x4 acc[4][4] = {};
#pragma unroll
  for (int ks = 0; ks < KS / 32; ++ks) {          // 12 k-steps of 32
    bf16x8 af[4], bf[4];
#pragma unroll
    for (int m = 0; m < 4; ++m)
      af[m] = *(const bf16x8*)(arow + (size_t)m * 16 * KS + ks * 32);
#pragma unroll
    for (int n = 0; n < 4; ++n)
      bf[n] = *(const bf16x8*)(brow + (size_t)n * 16 * KS + ks * 32);
#pragma unroll
    for (int m = 0; m < 4; ++m)
#pragma unroll
      for (int n = 0; n < 4; ++n)
        acc[m][n] = __builtin_amdgcn_mfma_f32_16x16x32_bf16(af[m], bf[n], acc[m][n], 0, 0, 0);
  }

#pragma unroll
  for (int n = 0; n < 4; ++n) {
    const int col = bn * 128 + wn * 64 + n * 16 + r;
    const float bs = bias[col];
#pragma unroll
    for (int m = 0; m < 4; ++m) {
      const int row0 = bm * 128 + wm * 64 + m * 16 + kg * 4;
#pragma unroll
      for (int j = 0; j < 4; ++j) {
        float z = acc[m][n][j] + bs;
        // softplus = max(z,0) + ln2*log2(1 + 2^(-|z|*log2e))
        float sp = fmaxf(z, 0.f) + LN2 * __log2f(1.0f + fast_exp2(-fabsf(z) * LOG2E));
        dtout[(size_t)(row0 + j) * DIM + col] = sp;
      }
    }
  }
}

// ---------- Kernel 2: per-chunk local scan -> P (decay product), S (local state) ----------
__global__ __launch_bounds__(256)
void scan_pass1(const float* __restrict__ dtw, const float* __restrict__ x,
                const float* __restrict__ Bin, const float* __restrict__ Alog,
                float* __restrict__ Pout, float* __restrict__ Sout) {
  __shared__ float4 Bl[CHUNK * NST / 4];          // 32*16 floats = 128 float4
  const int tid = threadIdx.x;
  const int bz = blockIdx.x;
  const int dt8 = bz & 7;                         // D/256 = 8
  const int c = (bz >> 3) & (NC - 1);
  const int b = bz >> 9;
  const int d = dt8 * 256 + tid;
  const int l0 = c * CHUNK;

  if (tid < CHUNK * NST / 4)
    Bl[tid] = ((const float4*)(Bin + ((size_t)b * LEN + l0) * NST))[tid];

  float A2[NST];
  {
    const float4* ap = (const float4*)(Alog + (size_t)d * NST);
#pragma unroll
    for (int q = 0; q < 4; ++q) {
      float4 v = ap[q];
      A2[q * 4 + 0] = -expf(v.x) * LOG2E;
      A2[q * 4 + 1] = -expf(v.y) * LOG2E;
      A2[q * 4 + 2] = -expf(v.z) * LOG2E;
      A2[q * 4 + 3] = -expf(v.w) * LOG2E;
    }
  }
  __syncthreads();

  float h[NST];
#pragma unroll
  for (int n = 0; n < NST; ++n) h[n] = 0.f;
  float sdt = 0.f;
  const float* dtp = dtw + ((size_t)b * LEN + l0) * DIM + d;
  const float* xp  = x   + ((size_t)b * LEN + l0) * DIM + d;

  float dtc = dtp[0], xc = xp[0];
#pragma unroll 4
  for (int i = 0; i < CHUNK; ++i) {
    float dtn = 0.f, xn = 0.f;
    if (i + 1 < CHUNK) { dtn = dtp[(size_t)(i + 1) * DIM]; xn = xp[(size_t)(i + 1) * DIM]; }
    float dtx = dtc * xc;
    sdt += dtc;
#pragma unroll
    for (int q = 0; q < 4; ++q) {
      float4 Bv = Bl[i * 4 + q];
      float e0 = fast_exp2(dtc * A2[q * 4 + 0]);
      float e1 = fast_exp2(dtc * A2[q * 4 + 1]);
      float e2 = fast_exp2(dtc * A2[q * 4 + 2]);
      float e3 = fast_exp2(dtc * A2[q * 4 + 3]);
      h[q * 4 + 0] = fmaf(e0, h[q * 4 + 0], dtx * Bv.x);
      h[q * 4 + 1] = fmaf(e1, h[q * 4 + 1], dtx * Bv.y);
      h[q * 4 + 2] = fmaf(e2, h[q * 4 + 2], dtx * Bv.z);
      h[q * 4 + 3] = fmaf(e3, h[q * 4 + 3], dtx * Bv.w);
    }
    dtc = dtn; xc = xn;
  }

  const size_t obase = ((size_t)(b * NC + c) * DIM + d) * NST;
#pragma unroll
  for (int q = 0; q < 4; ++q) {
    float4 pv;
    pv.x = fast_exp2(sdt * A2[q * 4 + 0]);
    pv.y = fast_exp2(sdt * A2[q * 4 + 1]);
    pv.z = fast_exp2(sdt * A2[q * 4 + 2]);
    pv.w = fast_exp2(sdt * A2[q * 4 + 3]);
    *(float4*)&Pout[obase + q * 4] = pv;
    float4 sv = {h[q * 4 + 0], h[q * 4 + 1], h[q * 4 + 2], h[q * 4 + 3]};
    *(float4*)&Sout[obase + q * 4] = sv;
  }
}

// ---------- Kernel 3: sequential combine over chunks; h_init written over P ----------
__global__ __launch_bounds__(256)
void chunk_combine(float* __restrict__ P, const float* __restrict__ S) {
  const int t = blockIdx.x * 256 + threadIdx.x;   // B*D*N = 65536 threads
  const int n = t & (NST - 1);
  const int d = (t >> 4) & (DIM - 1);
  const int b = t >> 15;
  float cur = 0.f;
#pragma unroll 8
  for (int c = 0; c < NC; ++c) {
    const size_t idx = ((size_t)(b * NC + c) * DIM + d) * NST + n;
    float p = P[idx];
    float s = S[idx];
    P[idx] = cur;                                  // h_init for chunk c
    cur = fmaf(p, cur, s);
  }
}

// ---------- Kernel 4: re-scan each chunk from h_init, emit y + x*D ----------
__global__ __launch_bounds__(256)
void scan_pass2(const float* __restrict__ dtw, const float* __restrict__ x,
                const float* __restrict__ Bin, const float* __restrict__ Cin,
                const float* __restrict__ Alog, const float* __restrict__ Dpar,
                const float* __restrict__ Hin, float* __restrict__ out) {
  __shared__ float4 Bl[CHUNK * NST / 4];
  __shared__ float4 Cl[CHUNK * NST / 4];
  const int tid = threadIdx.x;
  const int bz = blockIdx.x;
  const int dt8 = bz & 7;
  const int c = (bz >> 3) & (NC - 1);
  const int b = bz >> 9;
  const int d = dt8 * 256 + tid;
  const int l0 = c * CHUNK;

  if (tid < CHUNK * NST / 4)
    Bl[tid] = ((const float4*)(Bin + ((size_t)b * LEN + l0) * NST))[tid];
  else if (tid < CHUNK * NST / 2)
    Cl[tid - CHUNK * NST / 4] = ((const float4*)(Cin + ((size_t)b * LEN + l0) * NST))[tid - CHUNK * NST / 4];

  float A2[NST];
  {
    const float4* ap = (const float4*)(Alog + (size_t)d * NST);
#pragma unroll
    for (int q = 0; q < 4; ++q) {
      float4 v = ap[q];
      A2[q * 4 + 0] = -expf(v.x) * LOG2E;
      A2[q * 4 + 1] = -expf(v.y) * LOG2E;
      A2[q * 4 + 2] = -expf(v.z) * LOG2E;
      A2[q * 4 + 3] = -expf(v.w) * LOG2E;
    }
  }

  const size_t obase = ((size_t)(b * NC + c) * DIM + d) * NST;
  float h[NST];
#pragma unroll
  for (int q = 0; q < 4; ++q) {
    float4 hv = *(const float4*)&Hin[obase + q * 4];
    h[q * 4 + 0] = hv.x; h[q * 4 + 1] = hv.y; h[q * 4 + 2] = hv.z; h[q * 4 + 3] = hv.w;
  }
  const float dpar = Dpar[d];
  __syncthreads();

  const float* dtp = dtw + ((size_t)b * LEN + l0) * DIM + d;
  const float* xp  = x   + ((size_t)b * LEN + l0) * DIM + d;
  float* op        = out + ((size_t)b * LEN + l0) * DIM + d;

  float dtc = dtp[0], xc = xp[0];
#pragma unroll 4
  for (int i = 0; i < CHUNK; ++i) {
    float dtn = 0.f, xn = 0.f;
    if (i + 1 < CHUNK) { dtn = dtp[(size_t)(i + 1) * DIM]; xn = xp[(size_t)(i + 1) * DIM]; }
    float dtx = dtc * xc;
    float y0 = 0.f, y1 = 0.f, y2 = 0.f, y3 = 0.f;
#pragma unroll
    for (int q = 0; q < 4; ++q) {
      float4 Bv = Bl[i * 4 + q];
      float4 Cv = Cl[i * 4 + q];
      float e0 = fast_exp2(dtc * A2[q * 4 + 0]);
      float e1 = fast_exp2(dtc * A2[q * 4 + 1]);
      float e2 = fast_exp2(dtc * A2[q * 4 + 2]);
      float e3 = fast_exp2(dtc * A2[q * 4 + 3]);
      float hh0 = fmaf(e0, h[q * 4 + 0], dtx * Bv.x);
      float hh1 = fmaf(e1, h[q * 4 + 1], dtx * Bv.y);
      float hh2 = fmaf(e2, h[q * 4 + 2], dtx * Bv.z);
      float hh3 = fmaf(e3, h[q * 4 + 3], dtx * Bv.w);
      h[q * 4 + 0] = hh0; h[q * 4 + 1] = hh1; h[q * 4 + 2] = hh2; h[q * 4 + 3] = hh3;
      float yq = hh0 * Cv.x;
      yq = fmaf(hh1, Cv.y, yq);
      yq = fmaf(hh2, Cv.z, yq);
      yq = fmaf(hh3, Cv.w, yq);
      if (q == 0) y0 = yq; else if (q == 1) y1 = yq; else if (q == 2) y2 = yq; else y3 = yq;
    }
    op[(size_t)i * DIM] = fmaf(xc, dpar, (y0 + y1) + (y2 + y3));
    dtc = dtn; xc = xn;
  }
}

}  // namespace

extern "C" void kernel_launch(void* const* d_in, const int* in_sizes, int n_in,
                              void* d_out, int out_size, void* d_ws, size_t ws_size,
                              hipStream_t stream) {
  const float* x     = (const float*)d_in[0];
  const float* delta = (const float*)d_in[1];
  const float* Bin   = (const float*)d_in[2];
  const float* Cin   = (const float*)d_in[3];
  const float* Wdt   = (const float*)d_in[4];
  const float* bdt   = (const float*)d_in[5];
  const float* Alog  = (const float*)d_in[6];
  const float* Dpar  = (const float*)d_in[7];
  float* out = (float*)d_out;

  char* ws = (char*)d_ws;
  size_t off = 0;
  float* dtw = (float*)(ws + off); off += (size_t)BSZ * LEN * DIM * 4;          // 32 MiB
  float* P   = (float*)(ws + off); off += (size_t)BSZ * NC * DIM * NST * 4;     // 16 MiB
  float* S   = (float*)(ws + off); off += (size_t)BSZ * NC * DIM * NST * 4;     // 16 MiB
  unsigned short* Ad = (unsigned short*)(ws + off); off += (size_t)BSZ * LEN * KS * 2;  // 3 MiB
  unsigned short* Bd = (unsigned short*)(ws + off); off += (size_t)DIM * KS * 2;        // 1.5 MiB

  split_bf16<<<(BSZ * LEN * RNK + DIM * RNK) / 256, 256, 0, stream>>>(delta, Wdt, Ad, Bd);
  dt_mfma<<<(BSZ * LEN / 128) * (DIM / 128), 256, 0, stream>>>(Ad, Bd, bdt, dtw);
  scan_pass1<<<BSZ * NC * (DIM / 256), 256, 0, stream>>>(dtw, x, Bin, Alog, P, S);
  chunk_combine<<<BSZ * DIM * NST / 256, 256, 0, stream>>>(P, S);
  scan_pass2<<<BSZ * NC * (DIM / 256), 256, 0, stream>>>(dtw, x, Bin, Cin, Alog, Dpar, P, out);
}